// Round 1
// 1246.504 us; speedup vs baseline: 1.0190x; 1.0190x over previous
//
#include <hip/hip_runtime.h>

#define H_ 1024
#define W_ 1024
#define BATCH_ 4
#define CIN_ 32
#define COUT_ 32
#define KSZ_ 9

#define TH 16
#define TW 16
#define HALO_H 22            // TH + 6
#define HALO_W 24            // TW + 6, padded to multiple of 4 (one extra col each side-ish)
#define PITCH  25            // LDS row pitch in pixels (+1 pad to spread banks on writes)
#define NPIX (HALO_H * PITCH)   // 550
#define NTAPS 29

typedef __attribute__((ext_vector_type(8))) short short8;
typedef __attribute__((ext_vector_type(4))) float f32x4;

struct Tap { int dy, dx; };

// taps with dy^2+dx^2 <= 9 (disk support of psi; boundary taps are exactly 0 but harmless)
#define TAPS_LIST \
  {-3,0}, \
  {-2,-2},{-2,-1},{-2,0},{-2,1},{-2,2}, \
  {-1,-2},{-1,-1},{-1,0},{-1,1},{-1,2}, \
  {0,-3},{0,-2},{0,-1},{0,0},{0,1},{0,2},{0,3}, \
  {1,-2},{1,-1},{1,0},{1,1},{1,2}, \
  {2,-2},{2,-1},{2,0},{2,1},{2,2}, \
  {3,0}

__device__ const Tap g_taps[NTAPS] = { TAPS_LIST };

__device__ __forceinline__ unsigned short f2bf(float f) {
    unsigned int u = __builtin_bit_cast(unsigned int, f);
    u = (u + 0x7FFFu + ((u >> 16) & 1u)) >> 16;   // RNE
    return (unsigned short)u;
}

// Pack two fp32 -> one dword of 2x bf16 (RNE) in a single instruction.
__device__ __forceinline__ unsigned cvt_pk_bf16(float lo, float hi) {
    unsigned r;
    asm("v_cvt_pk_bf16_f32 %0, %1, %2" : "=v"(r) : "v"(lo), "v"(hi));
    return r;
}

// Build bf16 conv weights in A-fragment-friendly layout:
//   kw[t][q][oc][j]  (j = ic within quad, ic = q*8+j), flat bf16, 29*1024 elems.
__global__ void build_kw(const float* __restrict__ weight,
                         const float* __restrict__ psi,
                         unsigned short* __restrict__ kw) {
    int t = blockIdx.x;
    int a = g_taps[t].dy + 3;
    int bb = g_taps[t].dx + 3;
    float pv[KSZ_];
#pragma unroll
    for (int k = 0; k < KSZ_; ++k) pv[k] = psi[k * 49 + a * 7 + bb];
    for (int e = threadIdx.x; e < 1024; e += blockDim.x) {
        int q = e >> 8, rem = e & 255, oc = rem >> 3, j = rem & 7;
        int ic = q * 8 + j;
        float acc = 0.f;
#pragma unroll
        for (int k = 0; k < KSZ_; ++k) acc += pv[k] * weight[(oc * CIN_ + ic) * KSZ_ + k];
        kw[t * 1024 + e] = f2bf(acc);
    }
}

__global__ __launch_bounds__(256, 4)
void dconv(const float* __restrict__ x, const uint4* __restrict__ kw4,
           const float* __restrict__ bias, float* __restrict__ out) {
    // x tile in channel-quad planes: xt[q][row*PITCH + col] = 8 bf16 (ic q*8..q*8+7) of that pixel
    __shared__ uint4 xt[4][NPIX];   // 35,200 B

    const int tid = threadIdx.x;
    const unsigned bid = blockIdx.x;
    const int txt = bid & 63;
    const int tyt = (bid >> 6) & 63;
    const int b   = bid >> 12;
    const int x0 = txt * TW, y0 = tyt * TH;
    const size_t plane = (size_t)H_ * W_;

    // ---------------- staging: coalesced float4 loads + register transpose ----------------
    // item = (q, row, c4):  4 * 22 * 6 = 528 items.
    // Each item: 8 float4 loads (ch q*8..q*8+7, pixels gx0..gx0+3) -> 4 uint4 LDS writes.
    auto stage_item = [&](int it) {
        int q   = it / 132;            // 132 = 22*6
        int rem = it - q * 132;
        int row = rem / 6;
        int c4  = rem - row * 6;
        int gy  = y0 + row - 3;
        int gx0 = x0 + c4 * 4 - 4;     // halo cols span [x0-4, x0+19], 16B aligned
        bool rowin = (gy >= 0) & (gy < H_);
        const float* cb = x + (size_t)(b * CIN_ + q * 8) * plane
                            + (size_t)(rowin ? gy : 0) * W_;
        float v[8][4];
        if (rowin & (gx0 >= 0) & (gx0 + 4 <= W_)) {
            const float* p0 = cb + gx0;
#pragma unroll
            for (int j = 0; j < 8; ++j) {
                const float4 f = *reinterpret_cast<const float4*>(p0 + (size_t)j * plane);
                v[j][0] = f.x; v[j][1] = f.y; v[j][2] = f.z; v[j][3] = f.w;
            }
        } else {
#pragma unroll
            for (int j = 0; j < 8; ++j) {
#pragma unroll
                for (int c = 0; c < 4; ++c) {
                    int gx = gx0 + c;
                    bool inb = rowin & (gx >= 0) & (gx < W_);
                    v[j][c] = inb ? cb[(size_t)j * plane + gx] : 0.f;
                }
            }
        }
        uint4* dst = &xt[q][row * PITCH + c4 * 4];
#pragma unroll
        for (int c = 0; c < 4; ++c) {
            uint4 pk;
            pk.x = cvt_pk_bf16(v[0][c], v[1][c]);
            pk.y = cvt_pk_bf16(v[2][c], v[3][c]);
            pk.z = cvt_pk_bf16(v[4][c], v[5][c]);
            pk.w = cvt_pk_bf16(v[6][c], v[7][c]);
            dst[c] = pk;
        }
    };
    stage_item(tid);
    stage_item(tid + 256);
    if (tid < 528 - 512) stage_item(tid + 512);
    __syncthreads();

    // ---------------- compute: 29-tap implicit GEMM ----------------
    const int wv = tid >> 6, lane = tid & 63;
    const int p16 = lane & 15, quad = lane >> 4;

    f32x4 acc[4][2];
#pragma unroll
    for (int g = 0; g < 4; ++g) {
        acc[g][0] = f32x4{0.f, 0.f, 0.f, 0.f};
        acc[g][1] = f32x4{0.f, 0.f, 0.f, 0.f};
    }

    // Bias the base so every tap offset is a non-negative compile-time immediate:
    // min toff = -3*PITCH - 3 = -78.
    const uint4* bp = &xt[quad][0];
    const uint4* bq[4];
#pragma unroll
    for (int g = 0; g < 4; ++g)
        bq[g] = bp + (wv * 4 + g + 3) * PITCH + (p16 + 4) - 78;

    constexpr Tap taps[NTAPS] = { TAPS_LIST };
#pragma unroll
    for (int t = 0; t < NTAPS; ++t) {
        // A fragments: weights[oc = lane&15 (+16)][ic = quad*8 + j]
        short8 a0 = __builtin_bit_cast(short8, kw4[t * 128 + quad * 32 + p16]);
        short8 a1 = __builtin_bit_cast(short8, kw4[t * 128 + quad * 32 + 16 + p16]);
#pragma unroll
        for (int g = 0; g < 4; ++g) {
            // B fragment: x[ic = quad*8 + j][pixel = (row, x0 + lane&15) + tap offset]
            short8 bf = __builtin_bit_cast(short8, bq[g][taps[t].dy * PITCH + taps[t].dx + 78]);
            acc[g][0] = __builtin_amdgcn_mfma_f32_16x16x32_bf16(a0, bf, acc[g][0], 0, 0, 0);
            acc[g][1] = __builtin_amdgcn_mfma_f32_16x16x32_bf16(a1, bf, acc[g][1], 0, 0, 0);
        }
    }

    // ---------------- epilogue: D[row=oc: quad*4+reg][col=pixel: lane&15] ----------------
    float bv[2][4];
#pragma unroll
    for (int h = 0; h < 2; ++h)
#pragma unroll
        for (int i = 0; i < 4; ++i) bv[h][i] = bias[h * 16 + quad * 4 + i];

    float* ob = out + (size_t)b * COUT_ * plane;
#pragma unroll
    for (int g = 0; g < 4; ++g) {
        int gy = y0 + wv * 4 + g;
#pragma unroll
        for (int h = 0; h < 2; ++h) {
#pragma unroll
            for (int i = 0; i < 4; ++i) {
                int oc = h * 16 + quad * 4 + i;
                ob[(size_t)oc * plane + (size_t)gy * W_ + x0 + p16] = acc[g][h][i] + bv[h][i];
            }
        }
    }
}

extern "C" void kernel_launch(void* const* d_in, const int* in_sizes, int n_in,
                              void* d_out, int out_size, void* d_ws, size_t ws_size,
                              hipStream_t stream) {
    const float* x      = (const float*)d_in[0];
    const float* weight = (const float*)d_in[1];
    const float* bias   = (const float*)d_in[2];
    const float* psi    = (const float*)d_in[3];
    float* out = (float*)d_out;
    unsigned short* kw = (unsigned short*)d_ws;   // 29*1024 bf16 = 59,392 B

    hipLaunchKernelGGL(build_kw, dim3(NTAPS), dim3(256), 0, stream, weight, psi, kw);
    hipLaunchKernelGGL(dconv, dim3(BATCH_ * (H_ / TH) * (W_ / TW)), dim3(256), 0, stream,
                       x, (const uint4*)kw, bias, out);
    (void)in_sizes; (void)n_in; (void)out_size; (void)ws_size;
}